// Round 2
// baseline (633.435 us; speedup 1.0000x reference)
//
#include <hip/hip_runtime.h>
#include <hip/hip_bf16.h>
#include <stdint.h>

#define BATCH 16
#define SEQ   2048
#define DK    64
#define BQ    (BATCH * SEQ)

typedef float  f32x4  __attribute__((ext_vector_type(4)));
typedef __bf16 bf16x8 __attribute__((ext_vector_type(8)));
typedef unsigned short u16x8 __attribute__((ext_vector_type(8)));

#define MFMA16(a, b, c) __builtin_amdgcn_mfma_f32_16x16x32_bf16((a), (b), (c), 0, 0, 0)

__device__ __forceinline__ unsigned short bfbits(float f) {
  return __builtin_bit_cast(unsigned short, __float2bfloat16(f));
}

// load 8 contiguous f32 -> bf16 fragment
__device__ __forceinline__ bf16x8 fragld(const float* p) {
  f32x4 a = *(const f32x4*)p;
  f32x4 c = *(const f32x4*)(p + 4);
  bf16x8 r;
  r[0] = (__bf16)a[0]; r[1] = (__bf16)a[1]; r[2] = (__bf16)a[2]; r[3] = (__bf16)a[3];
  r[4] = (__bf16)c[0]; r[5] = (__bf16)c[1]; r[6] = (__bf16)c[2]; r[7] = (__bf16)c[3];
  return r;
}

__device__ __forceinline__ void cvt_store(unsigned short* dst, f32x4 a, f32x4 c) {
  u16x8 v;
  v[0] = bfbits(a[0]); v[1] = bfbits(a[1]); v[2] = bfbits(a[2]); v[3] = bfbits(a[3]);
  v[4] = bfbits(c[0]); v[5] = bfbits(c[1]); v[6] = bfbits(c[2]); v[7] = bfbits(c[3]);
  *(u16x8*)dst = v;
}

// Fused complex attention. One block = 64 query rows x one key-slice of one
// batch-head. 4 waves x 16 q-rows. LDS 40KB (K,V,P; pitch-64, XOR chunk
// swizzle) -> 4 blocks/CU. NS=2 split-K: linear softmax partials (no max
// subtraction needed: |S|/8 <~ 6) -> numerators+sums to ws, combined later.
template<int NS>
__global__ __launch_bounds__(256, 4)
void ck_attn_fused(const float* __restrict__ qr, const float* __restrict__ kr,
                   const float* __restrict__ vr, const float* __restrict__ qp,
                   const float* __restrict__ kp, const float* __restrict__ vp,
                   float* __restrict__ dout, float* __restrict__ wnum,
                   float* __restrict__ wsum)
{
  __shared__ __align__(16) unsigned short Kr[64][64], Kp[64][64];  // [key][d] bf16, swizzled
  __shared__ __align__(16) unsigned short Vr[64][64], Vp[64][64];  // [d][key] bf16, swizzled
  __shared__ __align__(16) unsigned short Pr[64][32], Pp[64][32];  // [q][key_half], swizzled

  const int b = blockIdx.y, qtile = blockIdx.x, slice = blockIdx.z;
  const int tid  = threadIdx.x;
  const int w    = tid >> 6, lane = tid & 63;
  const int lrow = lane & 15, lgrp = lane >> 4;

  const size_t bo = (size_t)b * SEQ * DK;
  const float* qrb = qr + bo; const float* qpb = qp + bo;
  const float* krb = kr + bo; const float* kpb = kp + bo;
  const float* vrb = vr + bo; const float* vpb = vp + bo;

  float* outR = dout;
  float* outP = dout + (size_t)BQ * DK;
  float* attn = dout + (size_t)2 * BQ * DK + ((size_t)b * SEQ + (size_t)qtile * 64) * SEQ;

  // ---- Q fragments (registers for whole kernel) ----
  const int qrow = qtile * 64 + w * 16 + lrow;
  bf16x8 aQ0, aQ1, aQ2, aQ3;
  {
    const float* pr0 = qrb + (size_t)qrow * DK + lgrp * 8;
    const float* pp0 = qpb + (size_t)qrow * DK + lgrp * 8;
    aQ0 = fragld(pr0);       // q_r d[0:32)
    aQ1 = fragld(pr0 + 32);  // q_r d[32:64)
    aQ2 = fragld(pp0);       // q_p d[0:32)
    aQ3 = fragld(pp0 + 32);  // q_p d[32:64)
  }

  f32x4 accRR[4] = {}, accPP[4] = {}, accRP[4] = {}, accPR[4] = {};
  float lsR[4] = {0.f, 0.f, 0.f, 0.f};
  float lsP[4] = {0.f, 0.f, 0.f, 0.f};

  const int kbeg = slice * (SEQ / NS);
  const int kend = kbeg + SEQ / NS;
  const int skK = tid >> 2, sdp = tid & 3;        // K staging: row, 16-d part
  const int skV = tid & 15, sdV = (tid >> 4) * 4; // V staging
  const int qloc = w * 16 + lgrp * 4;

  for (int k0 = kbeg; k0 < kend; k0 += 64) {
    __syncthreads();  // readers of previous tile done

    { // ---- stage K tile: coalesced rows, shared by all waves ----
      const float* gr = krb + (size_t)(k0 + skK) * DK + sdp * 16;
      const float* gp = kpb + (size_t)(k0 + skK) * DK + sdp * 16;
      f32x4 r0 = *(const f32x4*)gr,       r1 = *(const f32x4*)(gr + 4);
      f32x4 r2 = *(const f32x4*)(gr + 8), r3 = *(const f32x4*)(gr + 12);
      f32x4 p0 = *(const f32x4*)gp,       p1 = *(const f32x4*)(gp + 4);
      f32x4 p2 = *(const f32x4*)(gp + 8), p3 = *(const f32x4*)(gp + 12);
      const int c0 = sdp * 2, c1 = sdp * 2 + 1, sw = skK & 7;
      cvt_store(&Kr[skK][(c0 ^ sw) * 8], r0, r1);
      cvt_store(&Kr[skK][(c1 ^ sw) * 8], r2, r3);
      cvt_store(&Kp[skK][(c0 ^ sw) * 8], p0, p1);
      cvt_store(&Kp[skK][(c1 ^ sw) * 8], p2, p3);
    }
    #pragma unroll
    for (int pass = 0; pass < 4; ++pass) { // ---- stage V^T (bf16, swizzled) ----
      const int key = pass * 16 + skV;
      f32x4 a = *(const f32x4*)(vrb + (size_t)(k0 + key) * DK + sdV);
      f32x4 c = *(const f32x4*)(vpb + (size_t)(k0 + key) * DK + sdV);
      const int kc = key >> 3, kl = key & 7;
      #pragma unroll
      for (int j = 0; j < 4; ++j) {
        const int d = sdV + j;
        Vr[d][(kc ^ (d & 7)) * 8 + kl] = bfbits(a[j]);
        Vp[d][(kc ^ (d & 7)) * 8 + kl] = bfbits(c[j]);
      }
    }
    __syncthreads();

    #pragma unroll
    for (int h = 0; h < 2; ++h) {          // two 32-key halves
      #pragma unroll
      for (int t = 0; t < 2; ++t) {        // QK^T for 16 keys
        const int key16 = (h * 2 + t) * 16 + lrow;
        const int swk = key16 & 7;
        bf16x8 b0 = __builtin_bit_cast(bf16x8, *(const u16x8*)&Kr[key16][((lgrp    ) ^ swk) * 8]);
        bf16x8 b1 = __builtin_bit_cast(bf16x8, *(const u16x8*)&Kr[key16][((lgrp + 4) ^ swk) * 8]);
        bf16x8 b2 = __builtin_bit_cast(bf16x8, *(const u16x8*)&Kp[key16][((lgrp    ) ^ swk) * 8]);
        bf16x8 b3 = __builtin_bit_cast(bf16x8, *(const u16x8*)&Kp[key16][((lgrp + 4) ^ swk) * 8]);
        f32x4 t1 = {}, t2 = {}, sp = {};
        t1 = MFMA16(aQ0, b0, t1); t1 = MFMA16(aQ1, b1, t1);  // q_r.k_r
        t2 = MFMA16(aQ2, b2, t2); t2 = MFMA16(aQ3, b3, t2);  // q_p.k_p
        sp = MFMA16(aQ0, b2, sp); sp = MFMA16(aQ1, b3, sp);  // q_r.k_p
        sp = MFMA16(aQ2, b0, sp); sp = MFMA16(aQ3, b1, sp);  // q_p.k_r
        #pragma unroll
        for (int r = 0; r < 4; ++r) {
          float er = __expf((t1[r] - t2[r]) * 0.125f);
          float ep = __expf(sp[r] * 0.125f);
          lsR[r] += er; lsP[r] += ep;
          attn[(size_t)(qloc + r) * SEQ + k0 + key16] = er;   // unnormalized
          const int row = qloc + r, col = t * 16 + lrow;
          const int pc = ((col >> 3) ^ (row & 3)) * 8 + (col & 7);
          Pr[row][pc] = bfbits(er);   // per-wave-private: no barrier needed
          Pp[row][pc] = bfbits(ep);
        }
      }
      { // ---- PV for this 32-key half ----
        const int prow = w * 16 + lrow;
        bf16x8 apr = __builtin_bit_cast(bf16x8, *(const u16x8*)&Pr[prow][(lgrp ^ (prow & 3)) * 8]);
        bf16x8 app = __builtin_bit_cast(bf16x8, *(const u16x8*)&Pp[prow][(lgrp ^ (prow & 3)) * 8]);
        #pragma unroll
        for (int nt = 0; nt < 4; ++nt) {
          const int d = nt * 16 + lrow;
          const int cv = ((h * 4 + lgrp) ^ (d & 7)) * 8;
          bf16x8 bvr = __builtin_bit_cast(bf16x8, *(const u16x8*)&Vr[d][cv]);
          bf16x8 bvp = __builtin_bit_cast(bf16x8, *(const u16x8*)&Vp[d][cv]);
          accRR[nt] = MFMA16(apr, bvr, accRR[nt]);
          accPP[nt] = MFMA16(app, bvp, accPP[nt]);
          accRP[nt] = MFMA16(apr, bvp, accRP[nt]);
          accPR[nt] = MFMA16(app, bvr, accPR[nt]);
        }
      }
    }
  }

  // ---- reduce row sums across the 16 lanes of each lgrp group ----
  #pragma unroll
  for (int r = 0; r < 4; ++r) {
    float sR = lsR[r], sP = lsP[r];
    #pragma unroll
    for (int m = 1; m < 16; m <<= 1) {
      sR += __shfl_xor(sR, m, 64);
      sP += __shfl_xor(sP, m, 64);
    }
    lsR[r] = sR; lsP[r] = sP;
  }

  if (NS == 1) {
    float iR[4], iP[4];
    #pragma unroll
    for (int r = 0; r < 4; ++r) { iR[r] = 1.0f / lsR[r]; iP[r] = 1.0f / lsP[r]; }
    #pragma unroll
    for (int nt = 0; nt < 4; ++nt) {
      const int d = nt * 16 + lrow;
      #pragma unroll
      for (int r = 0; r < 4; ++r) {
        const size_t o = ((size_t)b * SEQ + qtile * 64 + qloc + r) * DK + d;
        outR[o] = accRR[nt][r] * iR[r] - accPP[nt][r] * iP[r];
        outP[o] = accRP[nt][r] * iR[r] + accPR[nt][r] * iP[r];
      }
    }
  } else {
    const size_t rowg = (size_t)b * SEQ + qtile * 64 + qloc;
    #pragma unroll
    for (int nt = 0; nt < 4; ++nt) {
      const int d = nt * 16 + lrow;
      #pragma unroll
      for (int r = 0; r < 4; ++r) {
        const size_t rr = rowg + r;
        wnum[((size_t)(slice * 4 + 0) * BQ + rr) * DK + d] = accRR[nt][r];
        wnum[((size_t)(slice * 4 + 1) * BQ + rr) * DK + d] = accPP[nt][r];
        wnum[((size_t)(slice * 4 + 2) * BQ + rr) * DK + d] = accRP[nt][r];
        wnum[((size_t)(slice * 4 + 3) * BQ + rr) * DK + d] = accPR[nt][r];
      }
    }
    if (lrow == 0) {
      #pragma unroll
      for (int r = 0; r < 4; ++r) {
        wsum[(size_t)(slice * 2 + 0) * BQ + rowg + r] = lsR[r];
        wsum[(size_t)(slice * 2 + 1) * BQ + rowg + r] = lsP[r];
      }
    }
  }
}

// Combine split-K partials: O = (sum numerators)/(sum row-sums), per element.
__global__ __launch_bounds__(256)
void ck_combine(const float* __restrict__ wnum, const float* __restrict__ wsum,
                float* __restrict__ dout)
{
  const size_t i4  = (size_t)blockIdx.x * 256 + threadIdx.x;  // f32x4 index
  const size_t row = i4 >> 4;
  const size_t base0 = row * DK + (i4 & 15) * 4;
  const size_t MAT = (size_t)BQ * DK;
  f32x4 rr = *(const f32x4*)(wnum + 0 * MAT + base0);
  rr += *(const f32x4*)(wnum + 4 * MAT + base0);
  f32x4 pp = *(const f32x4*)(wnum + 1 * MAT + base0);
  pp += *(const f32x4*)(wnum + 5 * MAT + base0);
  f32x4 rp = *(const f32x4*)(wnum + 2 * MAT + base0);
  rp += *(const f32x4*)(wnum + 6 * MAT + base0);
  f32x4 pr = *(const f32x4*)(wnum + 3 * MAT + base0);
  pr += *(const f32x4*)(wnum + 7 * MAT + base0);
  const float iR = 1.0f / (wsum[row] + wsum[2 * (size_t)BQ + row]);
  const float iP = 1.0f / (wsum[(size_t)BQ + row] + wsum[3 * (size_t)BQ + row]);
  *(f32x4*)(dout + base0)       = rr * iR - pp * iP;
  *(f32x4*)(dout + MAT + base0) = rp * iR + pr * iP;
}

// Normalize attn rows in place: one block per row.
__global__ __launch_bounds__(256)
void ck_attn_norm(float* __restrict__ attn)
{
  float* row = attn + (size_t)blockIdx.x * SEQ;
  const int t = threadIdx.x;
  f32x4 x0 = ((const f32x4*)row)[2 * t];
  f32x4 x1 = ((const f32x4*)row)[2 * t + 1];
  float s = x0[0] + x0[1] + x0[2] + x0[3] + x1[0] + x1[1] + x1[2] + x1[3];
  #pragma unroll
  for (int m = 1; m < 64; m <<= 1) s += __shfl_xor(s, m, 64);
  __shared__ float part[4];
  if ((t & 63) == 0) part[t >> 6] = s;
  __syncthreads();
  s = part[0] + part[1] + part[2] + part[3];
  const float r = 1.0f / s;
  x0 *= r;
  x1 *= r;
  ((f32x4*)row)[2 * t]     = x0;
  ((f32x4*)row)[2 * t + 1] = x1;
}

extern "C" void kernel_launch(void* const* d_in, const int* in_sizes, int n_in,
                              void* d_out, int out_size, void* d_ws, size_t ws_size,
                              hipStream_t stream)
{
  const float* qr = (const float*)d_in[0];
  const float* kr = (const float*)d_in[1];
  const float* vr = (const float*)d_in[2];
  const float* qp = (const float*)d_in[3];
  const float* kp = (const float*)d_in[4];
  const float* vp = (const float*)d_in[5];
  float* out = (float*)d_out;

  float* wnum = (float*)d_ws;
  float* wsum = wnum + (size_t)8 * BQ * DK;
  const size_t need = ((size_t)8 * BQ * DK + (size_t)4 * BQ) * sizeof(float);

  if (ws_size >= need) {
    dim3 g(SEQ / 64, BATCH, 2);
    ck_attn_fused<2><<<g, 256, 0, stream>>>(qr, kr, vr, qp, kp, vp, out, wnum, wsum);
    ck_combine<<<(BQ * DK / 4) / 256, 256, 0, stream>>>(wnum, wsum, out);
  } else {
    dim3 g(SEQ / 64, BATCH, 1);
    ck_attn_fused<1><<<g, 256, 0, stream>>>(qr, kr, vr, qp, kp, vp, out, wnum, wsum);
  }
  ck_attn_norm<<<BATCH * SEQ, 256, 0, stream>>>(out + (size_t)2 * BQ * DK);
}

// Round 3
// 302.266 us; speedup vs baseline: 2.0956x; 2.0956x over previous
//
#include <hip/hip_runtime.h>
#include <hip/hip_bf16.h>
#include <stdint.h>

#define BATCH 16
#define SEQ   2048
#define DK    64
#define BQ    (BATCH * SEQ)

typedef float  f32x4  __attribute__((ext_vector_type(4)));
typedef __bf16 bf16x8 __attribute__((ext_vector_type(8)));
typedef unsigned short u16x8 __attribute__((ext_vector_type(8)));

#define MFMA16(a, b, c) __builtin_amdgcn_mfma_f32_16x16x32_bf16((a), (b), (c), 0, 0, 0)

__device__ __forceinline__ unsigned short bfbits(float f) {
  return __builtin_bit_cast(unsigned short, __float2bfloat16(f));
}

// load 8 contiguous f32 -> bf16 fragment
__device__ __forceinline__ bf16x8 fragld(const float* p) {
  f32x4 a = *(const f32x4*)p;
  f32x4 c = *(const f32x4*)(p + 4);
  bf16x8 r;
  r[0] = (__bf16)a[0]; r[1] = (__bf16)a[1]; r[2] = (__bf16)a[2]; r[3] = (__bf16)a[3];
  r[4] = (__bf16)c[0]; r[5] = (__bf16)c[1]; r[6] = (__bf16)c[2]; r[7] = (__bf16)c[3];
  return r;
}

__device__ __forceinline__ void cvt_store(unsigned short* dst, f32x4 a, f32x4 c) {
  u16x8 v;
  v[0] = bfbits(a[0]); v[1] = bfbits(a[1]); v[2] = bfbits(a[2]); v[3] = bfbits(a[3]);
  v[4] = bfbits(c[0]); v[5] = bfbits(c[1]); v[6] = bfbits(c[2]); v[7] = bfbits(c[3]);
  *(u16x8*)dst = v;
}

// One block = 64 q-rows of one batch-head, full key sweep, 8 waves in two
// 4-wave groups (group g owns keys [g*1024, g*1024+1024), own 40KB LDS set).
// Pass A: QK^T + exp -> row sums only (recompute is cheap; MFMA ~5% busy).
// Pass B: QK^T again, E = exp/sum written NORMALIZED to attn (once, NT),
//         PV accumulated with normalized bf16 P. Group partials merge in LDS.
// No max-subtraction needed: |S|/8 <~ 6 fits f32 exp comfortably.
__global__ __launch_bounds__(512, 4)
void ck_attn(const float* __restrict__ qr, const float* __restrict__ kr,
             const float* __restrict__ vr, const float* __restrict__ qp,
             const float* __restrict__ kp, const float* __restrict__ vp,
             float* __restrict__ dout)
{
  __shared__ __align__(16) unsigned char lds[81920];

  const int tid  = threadIdx.x;
  const int w    = tid >> 6;
  const int g    = w >> 2;            // key-half group
  const int wq   = w & 3;             // wave within group -> 16 q-rows
  const int lane = tid & 63;
  const int lrow = lane & 15, lgrp = lane >> 4;
  const int ltid = tid & 255;         // thread id within group

  unsigned short (*Kr)[64] = (unsigned short(*)[64])(lds + g * 40960);
  unsigned short (*Kp)[64] = (unsigned short(*)[64])(lds + g * 40960 + 8192);
  unsigned short (*Vr)[64] = (unsigned short(*)[64])(lds + g * 40960 + 16384);
  unsigned short (*Vp)[64] = (unsigned short(*)[64])(lds + g * 40960 + 24576);
  unsigned short (*Pr)[32] = (unsigned short(*)[32])(lds + g * 40960 + 32768);
  unsigned short (*Pp)[32] = (unsigned short(*)[32])(lds + g * 40960 + 36864);

  // XCD-affinity swizzle: 512 blocks, 8 XCDs -> 64 consecutive logical ids
  // (= 2 whole batches) per XCD, so each XCD L2 holds one 4MB K/V working set.
  const int hw = blockIdx.x;
  const int logical = (hw & 7) * 64 + (hw >> 3);
  const int b = logical >> 5, qtile = logical & 31;

  const size_t bo = (size_t)b * SEQ * DK;
  const float* qrb = qr + bo; const float* qpb = qp + bo;
  const float* krb = kr + bo; const float* kpb = kp + bo;
  const float* vrb = vr + bo; const float* vpb = vp + bo;

  float* outR = dout;
  float* outP = dout + (size_t)BQ * DK;
  float* attn = dout + (size_t)2 * BQ * DK + ((size_t)b * SEQ + (size_t)qtile * 64) * SEQ;

  // ---- Q fragments (registers for whole kernel; both groups load same rows) ----
  const int qrow = qtile * 64 + wq * 16 + lrow;
  bf16x8 aQ0, aQ1, aQ2, aQ3;
  {
    const float* pr0 = qrb + (size_t)qrow * DK + lgrp * 8;
    const float* pp0 = qpb + (size_t)qrow * DK + lgrp * 8;
    aQ0 = fragld(pr0);       // q_r d[0:32)
    aQ1 = fragld(pr0 + 32);  // q_r d[32:64)
    aQ2 = fragld(pp0);       // q_p d[0:32)
    aQ3 = fragld(pp0 + 32);  // q_p d[32:64)
  }

  const int kbase = g * (SEQ / 2);
  const int skK = ltid >> 2, sdp = ltid & 3;        // K staging: row, 16-d part
  const int skV = ltid & 15, sdV = (ltid >> 4) * 4; // V staging
  const int qloc = wq * 16 + lgrp * 4;

  float lsR[4] = {0.f, 0.f, 0.f, 0.f};
  float lsP[4] = {0.f, 0.f, 0.f, 0.f};

  // ================= Pass A: row sums =================
  for (int i = 0; i < 16; ++i) {
    const int k0 = kbase + i * 64;
    __syncthreads();
    { // stage K tile (coalesced rows, shared by group's 4 waves)
      const float* gr = krb + (size_t)(k0 + skK) * DK + sdp * 16;
      const float* gp = kpb + (size_t)(k0 + skK) * DK + sdp * 16;
      f32x4 r0 = *(const f32x4*)gr,       r1 = *(const f32x4*)(gr + 4);
      f32x4 r2 = *(const f32x4*)(gr + 8), r3 = *(const f32x4*)(gr + 12);
      f32x4 p0 = *(const f32x4*)gp,       p1 = *(const f32x4*)(gp + 4);
      f32x4 p2 = *(const f32x4*)(gp + 8), p3 = *(const f32x4*)(gp + 12);
      const int c0 = sdp * 2, c1 = sdp * 2 + 1, sw = skK & 7;
      cvt_store(&Kr[skK][(c0 ^ sw) * 8], r0, r1);
      cvt_store(&Kr[skK][(c1 ^ sw) * 8], r2, r3);
      cvt_store(&Kp[skK][(c0 ^ sw) * 8], p0, p1);
      cvt_store(&Kp[skK][(c1 ^ sw) * 8], p2, p3);
    }
    __syncthreads();
    #pragma unroll
    for (int t = 0; t < 4; ++t) {
      const int key16 = t * 16 + lrow;
      const int swk = lrow & 7;
      bf16x8 b0 = __builtin_bit_cast(bf16x8, *(const u16x8*)&Kr[key16][((lgrp    ) ^ swk) * 8]);
      bf16x8 b1 = __builtin_bit_cast(bf16x8, *(const u16x8*)&Kr[key16][((lgrp + 4) ^ swk) * 8]);
      bf16x8 b2 = __builtin_bit_cast(bf16x8, *(const u16x8*)&Kp[key16][((lgrp    ) ^ swk) * 8]);
      bf16x8 b3 = __builtin_bit_cast(bf16x8, *(const u16x8*)&Kp[key16][((lgrp + 4) ^ swk) * 8]);
      f32x4 t1 = {}, t2 = {}, sp = {};
      t1 = MFMA16(aQ0, b0, t1); t1 = MFMA16(aQ1, b1, t1);  // q_r.k_r
      t2 = MFMA16(aQ2, b2, t2); t2 = MFMA16(aQ3, b3, t2);  // q_p.k_p
      sp = MFMA16(aQ0, b2, sp); sp = MFMA16(aQ1, b3, sp);  // q_r.k_p
      sp = MFMA16(aQ2, b0, sp); sp = MFMA16(aQ3, b1, sp);  // q_p.k_r
      #pragma unroll
      for (int r = 0; r < 4; ++r) {
        lsR[r] += __expf((t1[r] - t2[r]) * 0.125f);
        lsP[r] += __expf(sp[r] * 0.125f);
      }
    }
  }

  // ---- reduce sums across 16 cols, then across the two groups (LDS) ----
  #pragma unroll
  for (int r = 0; r < 4; ++r) {
    float sR = lsR[r], sP = lsP[r];
    #pragma unroll
    for (int m = 1; m < 16; m <<= 1) {
      sR += __shfl_xor(sR, m, 64);
      sP += __shfl_xor(sP, m, 64);
    }
    lsR[r] = sR; lsP[r] = sP;
  }
  float iR[4], iP[4];
  {
    float* sumx = (float*)(lds + 16384);  // overlays g0 V area (dead here); 2KB
    __syncthreads();
    if (lrow == 0) {
      #pragma unroll
      for (int r = 0; r < 4; ++r) {
        const int ix = ((g * 4 + wq) * 4 + lgrp) * 4 + r;
        sumx[ix]       = lsR[r];
        sumx[256 + ix] = lsP[r];
      }
    }
    __syncthreads();
    #pragma unroll
    for (int r = 0; r < 4; ++r) {
      const int i0 = ((0 * 4 + wq) * 4 + lgrp) * 4 + r;
      const int i1 = ((1 * 4 + wq) * 4 + lgrp) * 4 + r;
      iR[r] = 1.0f / (sumx[i0] + sumx[i1]);
      iP[r] = 1.0f / (sumx[256 + i0] + sumx[256 + i1]);
    }
    __syncthreads();
  }

  // ================= Pass B: normalized attn write + PV =================
  f32x4 accRR[4] = {}, accPP[4] = {}, accRP[4] = {}, accPR[4] = {};
  for (int i = 0; i < 16; ++i) {
    const int k0 = kbase + i * 64;
    __syncthreads();
    { // stage K
      const float* gr = krb + (size_t)(k0 + skK) * DK + sdp * 16;
      const float* gp = kpb + (size_t)(k0 + skK) * DK + sdp * 16;
      f32x4 r0 = *(const f32x4*)gr,       r1 = *(const f32x4*)(gr + 4);
      f32x4 r2 = *(const f32x4*)(gr + 8), r3 = *(const f32x4*)(gr + 12);
      f32x4 p0 = *(const f32x4*)gp,       p1 = *(const f32x4*)(gp + 4);
      f32x4 p2 = *(const f32x4*)(gp + 8), p3 = *(const f32x4*)(gp + 12);
      const int c0 = sdp * 2, c1 = sdp * 2 + 1, sw = skK & 7;
      cvt_store(&Kr[skK][(c0 ^ sw) * 8], r0, r1);
      cvt_store(&Kr[skK][(c1 ^ sw) * 8], r2, r3);
      cvt_store(&Kp[skK][(c0 ^ sw) * 8], p0, p1);
      cvt_store(&Kp[skK][(c1 ^ sw) * 8], p2, p3);
    }
    #pragma unroll
    for (int pass = 0; pass < 4; ++pass) { // stage V^T (bf16, swizzled)
      const int key = pass * 16 + skV;
      f32x4 a = *(const f32x4*)(vrb + (size_t)(k0 + key) * DK + sdV);
      f32x4 c = *(const f32x4*)(vpb + (size_t)(k0 + key) * DK + sdV);
      const int kc = key >> 3, kl = key & 7;
      #pragma unroll
      for (int j = 0; j < 4; ++j) {
        const int d = sdV + j;
        Vr[d][(kc ^ (d & 7)) * 8 + kl] = bfbits(a[j]);
        Vp[d][(kc ^ (d & 7)) * 8 + kl] = bfbits(c[j]);
      }
    }
    __syncthreads();

    #pragma unroll
    for (int h = 0; h < 2; ++h) {
      #pragma unroll
      for (int t = 0; t < 2; ++t) {
        const int key16 = (h * 2 + t) * 16 + lrow;
        const int swk = lrow & 7;
        bf16x8 b0 = __builtin_bit_cast(bf16x8, *(const u16x8*)&Kr[key16][((lgrp    ) ^ swk) * 8]);
        bf16x8 b1 = __builtin_bit_cast(bf16x8, *(const u16x8*)&Kr[key16][((lgrp + 4) ^ swk) * 8]);
        bf16x8 b2 = __builtin_bit_cast(bf16x8, *(const u16x8*)&Kp[key16][((lgrp    ) ^ swk) * 8]);
        bf16x8 b3 = __builtin_bit_cast(bf16x8, *(const u16x8*)&Kp[key16][((lgrp + 4) ^ swk) * 8]);
        f32x4 t1 = {}, t2 = {}, sp = {};
        t1 = MFMA16(aQ0, b0, t1); t1 = MFMA16(aQ1, b1, t1);
        t2 = MFMA16(aQ2, b2, t2); t2 = MFMA16(aQ3, b3, t2);
        sp = MFMA16(aQ0, b2, sp); sp = MFMA16(aQ1, b3, sp);
        sp = MFMA16(aQ2, b0, sp); sp = MFMA16(aQ3, b1, sp);
        #pragma unroll
        for (int r = 0; r < 4; ++r) {
          const float er = __expf((t1[r] - t2[r]) * 0.125f) * iR[r];  // normalized
          const float ep = __expf(sp[r] * 0.125f) * iP[r];
          __builtin_nontemporal_store(er, &attn[(size_t)(qloc + r) * SEQ + k0 + key16]);
          const int row = qloc + r, col = t * 16 + lrow;
          const int pc = ((col >> 3) ^ (row & 3)) * 8 + (col & 7);
          Pr[row][pc] = bfbits(er);   // per-wave-private rows: no barrier
          Pp[row][pc] = bfbits(ep);
        }
      }
      { // PV for this 32-key half (normalized P -> no final divide)
        const int prow = wq * 16 + lrow;
        bf16x8 apr = __builtin_bit_cast(bf16x8, *(const u16x8*)&Pr[prow][(lgrp ^ (prow & 3)) * 8]);
        bf16x8 app = __builtin_bit_cast(bf16x8, *(const u16x8*)&Pp[prow][(lgrp ^ (prow & 3)) * 8]);
        #pragma unroll
        for (int nt = 0; nt < 4; ++nt) {
          const int d = nt * 16 + lrow;
          const int cv = ((h * 4 + lgrp) ^ (d & 7)) * 8;
          bf16x8 bvr = __builtin_bit_cast(bf16x8, *(const u16x8*)&Vr[d][cv]);
          bf16x8 bvp = __builtin_bit_cast(bf16x8, *(const u16x8*)&Vp[d][cv]);
          accRR[nt] = MFMA16(apr, bvr, accRR[nt]);
          accPP[nt] = MFMA16(app, bvp, accPP[nt]);
          accRP[nt] = MFMA16(apr, bvp, accRP[nt]);
          accPR[nt] = MFMA16(app, bvr, accPR[nt]);
        }
      }
    }
  }

  // ================= Epilogue: merge groups, write O =================
  f32x4 oR[4], oP[4];
  #pragma unroll
  for (int nt = 0; nt < 4; ++nt) {
    oR[nt] = accRR[nt] - accPP[nt];
    oP[nt] = accRP[nt] + accPR[nt];
  }
  __syncthreads();
  f32x4* xch = (f32x4*)lds;  // overlays g0 K/V areas (dead); stride 9 de-banks
  if (g == 1) {
    #pragma unroll
    for (int nt = 0; nt < 4; ++nt) {
      xch[(size_t)(wq * 64 + lane) * 9 + nt]     = oR[nt];
      xch[(size_t)(wq * 64 + lane) * 9 + 4 + nt] = oP[nt];
    }
  }
  __syncthreads();
  if (g == 0) {
    #pragma unroll
    for (int nt = 0; nt < 4; ++nt) {
      oR[nt] += xch[(size_t)(wq * 64 + lane) * 9 + nt];
      oP[nt] += xch[(size_t)(wq * 64 + lane) * 9 + 4 + nt];
      const int d = nt * 16 + lrow;
      #pragma unroll
      for (int r = 0; r < 4; ++r) {
        const size_t o = ((size_t)b * SEQ + qtile * 64 + qloc + r) * DK + d;
        __builtin_nontemporal_store(oR[nt][r], &outR[o]);
        __builtin_nontemporal_store(oP[nt][r], &outP[o]);
      }
    }
  }
}

extern "C" void kernel_launch(void* const* d_in, const int* in_sizes, int n_in,
                              void* d_out, int out_size, void* d_ws, size_t ws_size,
                              hipStream_t stream)
{
  const float* qr = (const float*)d_in[0];
  const float* kr = (const float*)d_in[1];
  const float* vr = (const float*)d_in[2];
  const float* qp = (const float*)d_in[3];
  const float* kp = (const float*)d_in[4];
  const float* vp = (const float*)d_in[5];
  float* out = (float*)d_out;

  ck_attn<<<SEQ / 64 * BATCH, 512, 0, stream>>>(qr, kr, vr, qp, kp, vp, out);
}

// Round 4
// 299.900 us; speedup vs baseline: 2.1122x; 1.0079x over previous
//
#include <hip/hip_runtime.h>
#include <hip/hip_bf16.h>
#include <stdint.h>

#define BATCH 16
#define SEQ   2048
#define DK    64
#define BQ    (BATCH * SEQ)

typedef float  f32x4  __attribute__((ext_vector_type(4)));
typedef __bf16 bf16x8 __attribute__((ext_vector_type(8)));
typedef unsigned short u16x8 __attribute__((ext_vector_type(8)));
typedef unsigned short u16x4 __attribute__((ext_vector_type(4)));

#define MFMA16(a, b, c) __builtin_amdgcn_mfma_f32_16x16x32_bf16((a), (b), (c), 0, 0, 0)

__device__ __forceinline__ unsigned short bfbits(float f) {
  return __builtin_bit_cast(unsigned short, __float2bfloat16(f));
}

__device__ __forceinline__ bf16x8 fragld(const float* p) {
  f32x4 a = *(const f32x4*)p;
  f32x4 c = *(const f32x4*)(p + 4);
  bf16x8 r;
  r[0] = (__bf16)a[0]; r[1] = (__bf16)a[1]; r[2] = (__bf16)a[2]; r[3] = (__bf16)a[3];
  r[4] = (__bf16)c[0]; r[5] = (__bf16)c[1]; r[6] = (__bf16)c[2]; r[7] = (__bf16)c[3];
  return r;
}

__device__ __forceinline__ void cvt_store(unsigned short* dst, f32x4 a, f32x4 c) {
  u16x8 v;
  v[0] = bfbits(a[0]); v[1] = bfbits(a[1]); v[2] = bfbits(a[2]); v[3] = bfbits(a[3]);
  v[4] = bfbits(c[0]); v[5] = bfbits(c[1]); v[6] = bfbits(c[2]); v[7] = bfbits(c[3]);
  *(u16x8*)dst = v;
}

// One block = 64 q-rows of one batch-head, 8 waves in two 4-wave groups, each
// group owns half the key range with its own 40KB LDS set.
// Pass A: QK^T + exp -> row sums (recompute is cheap, MFMA mostly idle).
// Pass B: QK^T again; E normalized, bf16 -> P panels; PV with sign-flipped
//   (-Pp) fragments so O_r/O_p each use ONE accumulator set (32 AGPR);
//   attn written from P panels as 128B-contiguous NT rows (no partial lines).
// K tile for i+1 is register-prefetched across the compute phase (T14).
__global__ __launch_bounds__(512, 4)
void ck_attn(const float* __restrict__ qr, const float* __restrict__ kr,
             const float* __restrict__ vr, const float* __restrict__ qp,
             const float* __restrict__ kp, const float* __restrict__ vp,
             float* __restrict__ dout)
{
  __shared__ __align__(16) unsigned char lds[81920];

  const int tid  = threadIdx.x;
  const int w    = tid >> 6;
  const int g    = w >> 2;            // key-half group
  const int wq   = w & 3;             // wave within group -> 16 q-rows
  const int lane = tid & 63;
  const int lrow = lane & 15, lgrp = lane >> 4;
  const int ltid = tid & 255;

  unsigned short (*Kr)[64] = (unsigned short(*)[64])(lds + g * 40960);
  unsigned short (*Kp)[64] = (unsigned short(*)[64])(lds + g * 40960 + 8192);
  unsigned short (*Vr)[64] = (unsigned short(*)[64])(lds + g * 40960 + 16384);
  unsigned short (*Vp)[64] = (unsigned short(*)[64])(lds + g * 40960 + 24576);
  unsigned short (*Pr)[32] = (unsigned short(*)[32])(lds + g * 40960 + 32768);
  unsigned short (*Pp)[32] = (unsigned short(*)[32])(lds + g * 40960 + 36864);

  // XCD-affinity swizzle: 64 consecutive logical blocks (2 batch-heads) per XCD.
  const int hw = blockIdx.x;
  const int logical = (hw & 7) * 64 + (hw >> 3);
  const int b = logical >> 5, qtile = logical & 31;

  const size_t bo = (size_t)b * SEQ * DK;
  const float* qrb = qr + bo; const float* qpb = qp + bo;
  const float* krb = kr + bo; const float* kpb = kp + bo;
  const float* vrb = vr + bo; const float* vpb = vp + bo;

  float* outR = dout;
  float* outP = dout + (size_t)BQ * DK;
  float* attn = dout + (size_t)2 * BQ * DK + ((size_t)b * SEQ + (size_t)qtile * 64) * SEQ;

  // ---- Q fragments ----
  const int qrow = qtile * 64 + wq * 16 + lrow;
  bf16x8 aQ0, aQ1, aQ2, aQ3;
  {
    const float* pr0 = qrb + (size_t)qrow * DK + lgrp * 8;
    const float* pp0 = qpb + (size_t)qrow * DK + lgrp * 8;
    aQ0 = fragld(pr0);       // q_r d[0:32)
    aQ1 = fragld(pr0 + 32);  // q_r d[32:64)
    aQ2 = fragld(pp0);       // q_p d[0:32)
    aQ3 = fragld(pp0 + 32);  // q_p d[32:64)
  }

  const int kbase = g * (SEQ / 2);
  const int skK = ltid >> 2, sdp = ltid & 3;        // K staging: row, 16-col part
  const int skV = ltid & 15, sdV = (ltid >> 4) * 4; // V staging
  const int qloc = wq * 16 + lgrp * 4;

  // K prefetch registers (live across compute phases)
  f32x4 kA0, kA1, kA2, kA3, kB0, kB1, kB2, kB3;
  auto loadK = [&](int k0) {
    const float* gr = krb + (size_t)(k0 + skK) * DK + sdp * 16;
    const float* gp = kpb + (size_t)(k0 + skK) * DK + sdp * 16;
    kA0 = ((const f32x4*)gr)[0]; kA1 = ((const f32x4*)gr)[1];
    kA2 = ((const f32x4*)gr)[2]; kA3 = ((const f32x4*)gr)[3];
    kB0 = ((const f32x4*)gp)[0]; kB1 = ((const f32x4*)gp)[1];
    kB2 = ((const f32x4*)gp)[2]; kB3 = ((const f32x4*)gp)[3];
  };
  auto storeK = [&]() {
    const int c0 = sdp * 2, c1 = sdp * 2 + 1, sw = skK & 7;
    cvt_store(&Kr[skK][(c0 ^ sw) * 8], kA0, kA1);
    cvt_store(&Kr[skK][(c1 ^ sw) * 8], kA2, kA3);
    cvt_store(&Kp[skK][(c0 ^ sw) * 8], kB0, kB1);
    cvt_store(&Kp[skK][(c1 ^ sw) * 8], kB2, kB3);
  };

  float lsR[4] = {0.f, 0.f, 0.f, 0.f};
  float lsP[4] = {0.f, 0.f, 0.f, 0.f};

  // ================= Pass A: row sums =================
  loadK(kbase);
  for (int i = 0; i < 16; ++i) {
    const int k0 = kbase + i * 64;
    __syncthreads();
    storeK();
    __syncthreads();
    if (i < 15) loadK(k0 + 64);   // T14: in flight across compute
    #pragma unroll
    for (int t = 0; t < 4; ++t) {
      const int key16 = t * 16 + lrow;
      const int swk = lrow & 7;
      bf16x8 b0 = __builtin_bit_cast(bf16x8, *(const u16x8*)&Kr[key16][((lgrp    ) ^ swk) * 8]);
      bf16x8 b1 = __builtin_bit_cast(bf16x8, *(const u16x8*)&Kr[key16][((lgrp + 4) ^ swk) * 8]);
      bf16x8 b2 = __builtin_bit_cast(bf16x8, *(const u16x8*)&Kp[key16][((lgrp    ) ^ swk) * 8]);
      bf16x8 b3 = __builtin_bit_cast(bf16x8, *(const u16x8*)&Kp[key16][((lgrp + 4) ^ swk) * 8]);
      f32x4 t1 = {}, t2 = {}, sp = {};
      t1 = MFMA16(aQ0, b0, t1); t1 = MFMA16(aQ1, b1, t1);  // q_r.k_r
      t2 = MFMA16(aQ2, b2, t2); t2 = MFMA16(aQ3, b3, t2);  // q_p.k_p
      sp = MFMA16(aQ0, b2, sp); sp = MFMA16(aQ1, b3, sp);  // q_r.k_p
      sp = MFMA16(aQ2, b0, sp); sp = MFMA16(aQ3, b1, sp);  // q_p.k_r
      #pragma unroll
      for (int r = 0; r < 4; ++r) {
        lsR[r] += __expf((t1[r] - t2[r]) * 0.125f);
        lsP[r] += __expf(sp[r] * 0.125f);
      }
    }
  }

  // ---- reduce sums across 16 cols, prefetch pass-B K, exchange across groups ----
  #pragma unroll
  for (int r = 0; r < 4; ++r) {
    float sR = lsR[r], sP = lsP[r];
    #pragma unroll
    for (int m = 1; m < 16; m <<= 1) {
      sR += __shfl_xor(sR, m, 64);
      sP += __shfl_xor(sP, m, 64);
    }
    lsR[r] = sR; lsP[r] = sP;
  }
  loadK(kbase);                       // pass-B tile 0, overlaps the exchange
  float iR[4], iP[4];
  {
    float* sumx = (float*)lds;        // overlays g0 K area (dead between passes)
    __syncthreads();
    if (lrow == 0) {
      #pragma unroll
      for (int r = 0; r < 4; ++r) {
        const int ix = ((g * 4 + wq) * 4 + lgrp) * 4 + r;
        sumx[ix]       = lsR[r];
        sumx[256 + ix] = lsP[r];
      }
    }
    __syncthreads();
    #pragma unroll
    for (int r = 0; r < 4; ++r) {
      const int i0 = ((0 * 4 + wq) * 4 + lgrp) * 4 + r;
      const int i1 = ((1 * 4 + wq) * 4 + lgrp) * 4 + r;
      iR[r] = 1.0f / (sumx[i0] + sumx[i1]);
      iP[r] = 1.0f / (sumx[256 + i0] + sumx[256 + i1]);
    }
  }

  // ================= Pass B: PV + normalized attn =================
  const u16x8 SGN = {0x8000, 0x8000, 0x8000, 0x8000, 0x8000, 0x8000, 0x8000, 0x8000};
  f32x4 accR[4] = {}, accP[4] = {};   // single set each: O_r, O_p
  for (int i = 0; i < 16; ++i) {
    const int k0 = kbase + i * 64;
    __syncthreads();
    // V loads first (latency hides under K cvt+ds_write)
    f32x4 va0, va1, va2, va3, vc0, vc1, vc2, vc3;
    {
      const float* v0 = vrb + (size_t)(k0 + skV) * DK + sdV;
      const float* c0p = vpb + (size_t)(k0 + skV) * DK + sdV;
      va0 = *(const f32x4*)(v0);
      va1 = *(const f32x4*)(v0 + 16 * DK);
      va2 = *(const f32x4*)(v0 + 32 * DK);
      va3 = *(const f32x4*)(v0 + 48 * DK);
      vc0 = *(const f32x4*)(c0p);
      vc1 = *(const f32x4*)(c0p + 16 * DK);
      vc2 = *(const f32x4*)(c0p + 32 * DK);
      vc3 = *(const f32x4*)(c0p + 48 * DK);
    }
    storeK();   // no wait: regs already resident (prefetched)
    #pragma unroll
    for (int pass = 0; pass < 4; ++pass) {
      const f32x4 a = pass == 0 ? va0 : pass == 1 ? va1 : pass == 2 ? va2 : va3;
      const f32x4 c = pass == 0 ? vc0 : pass == 1 ? vc1 : pass == 2 ? vc2 : vc3;
      const int key = pass * 16 + skV;
      const int kc = key >> 3, kl = key & 7;
      #pragma unroll
      for (int j = 0; j < 4; ++j) {
        const int d = sdV + j;
        Vr[d][(kc ^ (d & 7)) * 8 + kl] = bfbits(a[j]);
        Vp[d][(kc ^ (d & 7)) * 8 + kl] = bfbits(c[j]);
      }
    }
    __syncthreads();
    if (i < 15) loadK(k0 + 64);   // T14

    #pragma unroll
    for (int h = 0; h < 2; ++h) {
      #pragma unroll
      for (int t = 0; t < 2; ++t) {
        const int key16 = (h * 2 + t) * 16 + lrow;
        const int swk = lrow & 7;
        bf16x8 b0 = __builtin_bit_cast(bf16x8, *(const u16x8*)&Kr[key16][((lgrp    ) ^ swk) * 8]);
        bf16x8 b1 = __builtin_bit_cast(bf16x8, *(const u16x8*)&Kr[key16][((lgrp + 4) ^ swk) * 8]);
        bf16x8 b2 = __builtin_bit_cast(bf16x8, *(const u16x8*)&Kp[key16][((lgrp    ) ^ swk) * 8]);
        bf16x8 b3 = __builtin_bit_cast(bf16x8, *(const u16x8*)&Kp[key16][((lgrp + 4) ^ swk) * 8]);
        f32x4 t1 = {}, t2 = {}, sp = {};
        t1 = MFMA16(aQ0, b0, t1); t1 = MFMA16(aQ1, b1, t1);
        t2 = MFMA16(aQ2, b2, t2); t2 = MFMA16(aQ3, b3, t2);
        sp = MFMA16(aQ0, b2, sp); sp = MFMA16(aQ1, b3, sp);
        sp = MFMA16(aQ2, b0, sp); sp = MFMA16(aQ3, b1, sp);
        #pragma unroll
        for (int r = 0; r < 4; ++r) {
          const float er = __expf((t1[r] - t2[r]) * 0.125f) * iR[r];
          const float ep = __expf(sp[r] * 0.125f) * iP[r];
          const int row = qloc + r, col = t * 16 + lrow;
          const int pc = ((col >> 3) ^ (row & 3)) * 8 + (col & 7);
          Pr[row][pc] = bfbits(er);   // wave-private rows: no barrier
          Pp[row][pc] = bfbits(ep);
        }
      }
      { // PV: accR += Pr.Vr + (-Pp).Vp ; accP += Pr.Vp + Pp.Vr
        const int prow = wq * 16 + lrow;
        u16x8 uar = *(const u16x8*)&Pr[prow][(lgrp ^ (prow & 3)) * 8];
        u16x8 uap = *(const u16x8*)&Pp[prow][(lgrp ^ (prow & 3)) * 8];
        u16x8 uan = uap ^ SGN;
        bf16x8 apr = __builtin_bit_cast(bf16x8, uar);
        bf16x8 app = __builtin_bit_cast(bf16x8, uap);
        bf16x8 apn = __builtin_bit_cast(bf16x8, uan);
        #pragma unroll
        for (int nt = 0; nt < 4; ++nt) {
          const int d = nt * 16 + lrow;
          const int cv = ((h * 4 + lgrp) ^ (d & 7)) * 8;
          bf16x8 bvr = __builtin_bit_cast(bf16x8, *(const u16x8*)&Vr[d][cv]);
          bf16x8 bvp = __builtin_bit_cast(bf16x8, *(const u16x8*)&Vp[d][cv]);
          accR[nt] = MFMA16(apr, bvr, accR[nt]);
          accR[nt] = MFMA16(apn, bvp, accR[nt]);
          accP[nt] = MFMA16(apr, bvp, accP[nt]);
          accP[nt] = MFMA16(app, bvr, accP[nt]);
        }
      }
      { // attn write: bf16-rounded E_r, 128B-contiguous rows, NT
        const int arow = wq * 16 + (lane >> 2);
        const int j = lane & 3;
        const int pcA = (((j >> 1) ^ (arow & 3)) * 8) + (j & 1) * 4;
        const int pcB = (((2 + (j >> 1)) ^ (arow & 3)) * 8) + (j & 1) * 4;
        u16x4 ua = *(const u16x4*)&Pr[arow][pcA];
        u16x4 ub = *(const u16x4*)&Pr[arow][pcB];
        f32x4 fa, fb;
        #pragma unroll
        for (int q = 0; q < 4; ++q) {
          fa[q] = __builtin_bit_cast(float, (unsigned)ua[q] << 16);
          fb[q] = __builtin_bit_cast(float, (unsigned)ub[q] << 16);
        }
        float* dst = attn + (size_t)arow * SEQ + k0 + h * 32 + j * 4;
        __builtin_nontemporal_store(fa, (f32x4*)dst);
        __builtin_nontemporal_store(fb, (f32x4*)(dst + 16));
      }
    }
  }

  // ================= Epilogue: merge groups, write O =================
  __syncthreads();
  f32x4* xch = (f32x4*)lds;  // stride 9 de-banks
  if (g == 1) {
    #pragma unroll
    for (int nt = 0; nt < 4; ++nt) {
      xch[(size_t)(wq * 64 + lane) * 9 + nt]     = accR[nt];
      xch[(size_t)(wq * 64 + lane) * 9 + 4 + nt] = accP[nt];
    }
  }
  __syncthreads();
  if (g == 0) {
    #pragma unroll
    for (int nt = 0; nt < 4; ++nt) {
      f32x4 vR = accR[nt] + xch[(size_t)(wq * 64 + lane) * 9 + nt];
      f32x4 vP = accP[nt] + xch[(size_t)(wq * 64 + lane) * 9 + 4 + nt];
      const int d = nt * 16 + lrow;
      #pragma unroll
      for (int r = 0; r < 4; ++r) {
        const size_t o = ((size_t)b * SEQ + qtile * 64 + qloc + r) * DK + d;
        __builtin_nontemporal_store(vR[r], &outR[o]);
        __builtin_nontemporal_store(vP[r], &outP[o]);
      }
    }
  }
}

extern "C" void kernel_launch(void* const* d_in, const int* in_sizes, int n_in,
                              void* d_out, int out_size, void* d_ws, size_t ws_size,
                              hipStream_t stream)
{
  const float* qr = (const float*)d_in[0];
  const float* kr = (const float*)d_in[1];
  const float* vr = (const float*)d_in[2];
  const float* qp = (const float*)d_in[3];
  const float* kp = (const float*)d_in[4];
  const float* vp = (const float*)d_in[5];
  float* out = (float*)d_out;

  ck_attn<<<SEQ / 64 * BATCH, 512, 0, stream>>>(qr, kr, vr, qp, kp, vp, out);
}